// Round 2
// baseline (471.109 us; speedup 1.0000x reference)
//
#include <hip/hip_runtime.h>

// ---------- types ----------
typedef __bf16 bf16x8 __attribute__((ext_vector_type(8)));
typedef float  floatx4 __attribute__((ext_vector_type(4)));
typedef unsigned short ushortx8 __attribute__((ext_vector_type(8)));
typedef unsigned short ushortx4 __attribute__((ext_vector_type(4)));
typedef unsigned short ushortx2 __attribute__((ext_vector_type(2)));

__device__ __forceinline__ float bf2f(unsigned short u) {
    return __uint_as_float(((unsigned)u) << 16);
}
__device__ __forceinline__ unsigned short f2bf(float f) {
    unsigned u = __float_as_uint(f);
    return (unsigned short)((u + 0x7FFFu + ((u >> 16) & 1u)) >> 16);
}

// ---------- conversion / CSR helpers ----------
// fp32 [n] -> bf16 [n], vectorized x4 (n must be divisible by 4 — true here: 512|F)
__global__ void cvt_f32_bf16_kernel(const float* __restrict__ in,
                                    unsigned short* __restrict__ out, int n4) {
    int i = blockIdx.x * blockDim.x + threadIdx.x;
    if (i >= n4) return;
    float4 v = ((const float4*)in)[i];
    ushortx4 o;
    o[0] = f2bf(v.x); o[1] = f2bf(v.y); o[2] = f2bf(v.z); o[3] = f2bf(v.w);
    ((ushortx4*)out)[i] = o;
}

// fp32 K x N -> bf16 N x K (transpose + convert); small matrices only
__global__ void transpose_cvt_kernel(const float* __restrict__ in,
                                     unsigned short* __restrict__ out,
                                     int K, int N) {
    int idx = blockIdx.x * blockDim.x + threadIdx.x;
    if (idx >= K * N) return;
    int k = idx / N, n = idx - k * N;
    out[n * K + k] = f2bf(in[idx]);
}

__global__ void init_head_kernel(int* __restrict__ head, int n) {
    int i = blockIdx.x * blockDim.x + threadIdx.x;
    if (i < n) head[i] = -1;
}

__global__ void build_list_kernel(const int* __restrict__ ei, int E,
                                  int* __restrict__ head, int* __restrict__ nxt) {
    int e = blockIdx.x * blockDim.x + threadIdx.x;
    if (e >= E) return;
    int d = ei[E + e];                       // dst row of edge_index
    nxt[e] = atomicExch(&head[d], e);        // LIFO per-dst list
}

// ---------- GEMM: C[M,N] = A[M,K] @ B[K,N] + bias; A bf16 row-major, Bt = B^T bf16 (N x K) ----------
#define BM 128
#define BN 128
#define BK 32
#define KPAD 8   // row stride 40 elems (80B): 16B-aligned, 2-way banks (free)

__global__ __launch_bounds__(256) void gemm_bt_bias(
    const unsigned short* __restrict__ A,    // M x K  (bf16 bits)
    const unsigned short* __restrict__ Bt,   // N x K  (bf16 bits)
    const float* __restrict__ bias,          // N (fp32)
    unsigned short* __restrict__ C,          // M x N  (bf16 bits)
    int M, int N, int K)
{
    __shared__ unsigned short As[BM][BK + KPAD];
    __shared__ unsigned short Bs[BN][BK + KPAD];

    const int tid  = threadIdx.x;
    const int lane = tid & 63;
    const int wave = tid >> 6;
    const int bM = blockIdx.y * BM;
    const int bN = blockIdx.x * BN;

    const int wm = (wave >> 1) * 64;   // wave sub-tile origin (2x2 waves)
    const int wn = (wave & 1) * 64;

    const int q    = lane >> 4;        // 0..3
    const int mrow = lane & 15;

    floatx4 acc[4][4];
#pragma unroll
    for (int i = 0; i < 4; i++)
#pragma unroll
        for (int j = 0; j < 4; j++) acc[i][j] = (floatx4)(0.0f);

    for (int kt = 0; kt < K; kt += BK) {
#pragma unroll
        for (int i = 0; i < 2; i++) {
            int c   = i * 256 + tid;
            int row = c >> 2;
            int kg  = (c & 3) << 3;
            int gr = bM + row; if (gr >= M) gr = M - 1;   // clamp: only unstored rows polluted
            ushortx8 va = *(const ushortx8*)(A  + (size_t)gr * K + kt + kg);
            *(ushortx8*)&As[row][kg] = va;
            int gb = bN + row;                            // grid.x chosen so gb < N always
            ushortx8 vb = *(const ushortx8*)(Bt + (size_t)gb * K + kt + kg);
            *(ushortx8*)&Bs[row][kg] = vb;
        }
        __syncthreads();

        bf16x8 af[4], bfv[4];
#pragma unroll
        for (int mi = 0; mi < 4; mi++)
            af[mi] = *(const bf16x8*)&As[wm + mi * 16 + mrow][q * 8];
#pragma unroll
        for (int ni = 0; ni < 4; ni++)
            bfv[ni] = *(const bf16x8*)&Bs[wn + ni * 16 + mrow][q * 8];
#pragma unroll
        for (int mi = 0; mi < 4; mi++)
#pragma unroll
            for (int ni = 0; ni < 4; ni++)
                acc[mi][ni] = __builtin_amdgcn_mfma_f32_16x16x32_bf16(
                    af[mi], bfv[ni], acc[mi][ni], 0, 0, 0);
        __syncthreads();
    }

    // epilogue: C/D layout col = lane&15, row = q*4 + r  (m89/m91-verified)
#pragma unroll
    for (int ni = 0; ni < 4; ni++) {
        int col = bN + wn + ni * 16 + mrow;
        float bv = bias[col];
#pragma unroll
        for (int mi = 0; mi < 4; mi++) {
#pragma unroll
            for (int r = 0; r < 4; r++) {
                int row = bM + wm + mi * 16 + q * 4 + r;
                if (row < M)
                    C[(size_t)row * N + col] = f2bf(acc[mi][ni][r] + bv);
            }
        }
    }
}

// ---------- propagate step: one wave per destination node ----------
template <int VEC> struct VecT;
template <> struct VecT<8> { typedef ushortx8 type; };
template <> struct VecT<2> { typedef ushortx2 type; };

// cur: bf16 [Nn, F];  out: bf16 [Nn, F] or fp32 [Nn, F] (OUT_F32)
template <int VEC, bool ADD_SELF, bool RELU, bool OUT_F32>
__global__ __launch_bounds__(256) void prop_step_kernel(
    const unsigned short* __restrict__ cur,
    void* __restrict__ outp,
    const int* __restrict__ head,
    const int* __restrict__ nxt,
    const int* __restrict__ esrc,
    const int* __restrict__ emask,
    int kval, int Nn)
{
    typedef typename VecT<VEC>::type VT;
    const int w = blockIdx.x * 4 + (threadIdx.x >> 6);
    if (w >= Nn) return;
    const int lane = threadIdx.x & 63;
    const int F = VEC * 64;
    const size_t off = (size_t)w * F + lane * VEC;

    float acc[VEC];
    if (ADD_SELF) {
        VT v = *(const VT*)(cur + off);
#pragma unroll
        for (int i = 0; i < VEC; i++) acc[i] = bf2f(v[i]);
    } else {
#pragma unroll
        for (int i = 0; i < VEC; i++) acc[i] = 0.0f;
    }

    for (int e = head[w]; e >= 0; e = nxt[e]) {
        if (emask[e] == kval) {
            int s = esrc[e];
            VT v = *(const VT*)(cur + (size_t)s * F + lane * VEC);
#pragma unroll
            for (int i = 0; i < VEC; i++) acc[i] += bf2f(v[i]);
        }
    }

#pragma unroll
    for (int i = 0; i < VEC; i++)
        if (RELU && acc[i] < 0.0f) acc[i] = 0.0f;

    if (OUT_F32) {
        float* out = (float*)outp;
#pragma unroll
        for (int i = 0; i < VEC; i++) out[off + i] = acc[i];
    } else {
        VT o;
#pragma unroll
        for (int i = 0; i < VEC; i++) o[i] = f2bf(acc[i]);
        *(VT*)((unsigned short*)outp + off) = o;
    }
}

// ---------- launch ----------
extern "C" void kernel_launch(void* const* d_in, const int* in_sizes, int n_in,
                              void* d_out, int out_size, void* d_ws, size_t ws_size,
                              hipStream_t stream)
{
    const float* x  = (const float*)d_in[0];       // [Nn, 512] fp32
    const int*   ei = (const int*)d_in[1];         // [2, E] int32: src row then dst row
    const int*   em = (const int*)d_in[2];         // [E]
    const float* W1 = (const float*)d_in[5];       // [512,512] fp32
    const float* b1 = (const float*)d_in[6];       // [512]
    const float* W2 = (const float*)d_in[7];       // [512,128] fp32
    const float* b2 = (const float*)d_in[8];       // [128]

    const int FIN = 512, FOUT = 128;
    const int Nn = in_sizes[0] / FIN;   // 60000
    const int E  = in_sizes[2];         // 160000

    // workspace carve-out (~155 MB)
    char* ws = (char*)d_ws;
    size_t off = 0;
    auto alloc = [&](size_t bytes) -> char* {
        char* p = ws + off;
        off += (bytes + 255) & ~(size_t)255;
        return p;
    };
    unsigned short* W1t = (unsigned short*)alloc((size_t)FIN * FIN * 2);
    unsigned short* W2t = (unsigned short*)alloc((size_t)FIN * FOUT * 2);
    unsigned short* xb  = (unsigned short*)alloc((size_t)Nn * FIN * 2); // reused as A1 after GEMM1
    unsigned short* h1  = (unsigned short*)alloc((size_t)Nn * FIN * 2); // reused as B1 (relu'd)
    unsigned short* h2  = (unsigned short*)alloc((size_t)Nn * FOUT * 2);
    unsigned short* A2  = (unsigned short*)alloc((size_t)Nn * FOUT * 2);
    int* head = (int*)alloc((size_t)Nn * 4);
    int* nxt  = (int*)alloc((size_t)E * 4);
    unsigned short* A1 = xb;            // alias: xb dead after GEMM1
    (void)ws_size; (void)n_in; (void)out_size;

    // 1) convert x to bf16; transpose+convert weights to B^T bf16
    cvt_f32_bf16_kernel<<<((Nn * FIN / 4) + 255) / 256, 256, 0, stream>>>(x, xb, Nn * FIN / 4);
    transpose_cvt_kernel<<<(FIN * FIN + 255) / 256, 256, 0, stream>>>(W1, W1t, FIN, FIN);
    transpose_cvt_kernel<<<(FIN * FOUT + 255) / 256, 256, 0, stream>>>(W2, W2t, FIN, FOUT);

    // 2) per-dst linked lists
    init_head_kernel<<<(Nn + 255) / 256, 256, 0, stream>>>(head, Nn);
    build_list_kernel<<<(E + 255) / 256, 256, 0, stream>>>(ei, E, head, nxt);

    // 3) h1 = x @ W1 + b1   (bf16 in, bf16 out, fp32 accum)
    {
        dim3 grid(FIN / BN, (Nn + BM - 1) / BM);
        gemm_bt_bias<<<grid, 256, 0, stream>>>(xb, W1t, b1, h1, Nn, FIN, FIN);
    }

    // 4) P1 step0: A1 = sum_{mask==0} h1[src];  step1: B1 = relu(A1 + sum_{mask==1} A1[src])
    {
        int grid = (Nn + 3) / 4;
        prop_step_kernel<8, false, false, false><<<grid, 256, 0, stream>>>(h1, A1, head, nxt, ei, em, 0, Nn);
        prop_step_kernel<8, true,  true,  false><<<grid, 256, 0, stream>>>(A1, h1, head, nxt, ei, em, 1, Nn);
    }

    // 5) h2 = B1 @ W2 + b2
    {
        dim3 grid(FOUT / BN, (Nn + BM - 1) / BM);
        gemm_bt_bias<<<grid, 256, 0, stream>>>(h1, W2t, b2, h2, Nn, FOUT, FIN);
    }

    // 6) P2 step0: A2 = sum_{mask==0} h2[src];  step1: out = A2 + sum_{mask==1} A2[src]  (fp32 out)
    {
        int grid = (Nn + 3) / 4;
        prop_step_kernel<2, false, false, false><<<grid, 256, 0, stream>>>(h2, A2, head, nxt, ei, em, 0, Nn);
        prop_step_kernel<2, true,  false, true ><<<grid, 256, 0, stream>>>(A2, d_out, head, nxt, ei, em, 1, Nn);
    }
}

// Round 3
// 453.172 us; speedup vs baseline: 1.0396x; 1.0396x over previous
//
#include <hip/hip_runtime.h>

// ---------- types ----------
typedef __bf16 bf16x8 __attribute__((ext_vector_type(8)));
typedef float  floatx4 __attribute__((ext_vector_type(4)));
typedef unsigned short ushortx8 __attribute__((ext_vector_type(8)));
typedef unsigned short ushortx4 __attribute__((ext_vector_type(4)));
typedef unsigned short ushortx2 __attribute__((ext_vector_type(2)));

__device__ __forceinline__ float bf2f(unsigned short u) {
    return __uint_as_float(((unsigned)u) << 16);
}
__device__ __forceinline__ unsigned short f2bf(float f) {
    unsigned u = __float_as_uint(f);
    return (unsigned short)((u + 0x7FFFu + ((u >> 16) & 1u)) >> 16);
}

// async global->LDS, 16B per lane; lds dest = wave-uniform base + lane*16
__device__ __forceinline__ void gload_lds16(const unsigned short* g, unsigned short* l) {
    __builtin_amdgcn_global_load_lds(
        (const __attribute__((address_space(1))) void*)g,
        (__attribute__((address_space(3))) void*)l, 16, 0, 0);
}

// ---------- conversion / CSR helpers ----------
__global__ void cvt_f32_bf16_kernel(const float* __restrict__ in,
                                    unsigned short* __restrict__ out, int n4) {
    int i = blockIdx.x * blockDim.x + threadIdx.x;
    if (i >= n4) return;
    float4 v = ((const float4*)in)[i];
    ushortx4 o;
    o[0] = f2bf(v.x); o[1] = f2bf(v.y); o[2] = f2bf(v.z); o[3] = f2bf(v.w);
    ((ushortx4*)out)[i] = o;
}

__global__ void transpose_cvt_kernel(const float* __restrict__ in,
                                     unsigned short* __restrict__ out,
                                     int K, int N) {
    int idx = blockIdx.x * blockDim.x + threadIdx.x;
    if (idx >= K * N) return;
    int k = idx / N, n = idx - k * N;
    out[n * K + k] = f2bf(in[idx]);
}

__global__ void init_head_kernel(int* __restrict__ head, int n) {
    int i = blockIdx.x * blockDim.x + threadIdx.x;
    if (i < n) head[i] = -1;
}

__global__ void build_list_kernel(const int* __restrict__ ei, int E,
                                  int* __restrict__ head, int* __restrict__ nxt) {
    int e = blockIdx.x * blockDim.x + threadIdx.x;
    if (e >= E) return;
    int d = ei[E + e];
    nxt[e] = atomicExch(&head[d], e);
}

// ---------- GEMM: C[M,N] = A[M,K] @ B[K,N] + bias; A bf16 row-major, Bt = B^T bf16 (N x K) ----------
// m97-style: global_load_lds(16B) stages tiles in MFMA-fragment order; conflict-free ds_read_b128;
// LDS-repacked epilogue for coalesced 16B/lane C stores.
#define BM 128
#define BN 128
#define BK 32

__global__ __launch_bounds__(256) void gemm_bt_bias(
    const unsigned short* __restrict__ A,    // M x K  (bf16 bits)
    const unsigned short* __restrict__ Bt,   // N x K  (bf16 bits)
    const float* __restrict__ bias,          // N (fp32)
    unsigned short* __restrict__ C,          // M x N  (bf16 bits)
    int M, int N, int K)
{
    // Sh[0..4095]  = A-tile: 8 groups x (64 lanes x 8 elems). group g, lane l holds
    //                A[bM+g*16+(l&15)][kt+(l>>4)*8 + 0..7]  (exact MFMA A-frag order)
    // Sh[4096..]   = B-tile, same layout over N rows of Bt.
    __shared__ unsigned short Sh[8192];      // 16 KB
    unsigned short (*As)[512] = (unsigned short(*)[512])Sh;
    unsigned short (*Bs)[512] = (unsigned short(*)[512])(Sh + 4096);

    const int tid  = threadIdx.x;
    const int lane = tid & 63;
    const int wave = tid >> 6;
    const int bM = blockIdx.y * BM;
    const int bN = blockIdx.x * BN;
    const int wm = (wave >> 1) * 64;   // wave sub-tile origin (2x2 waves)
    const int wn = (wave & 1) * 64;
    const int q    = lane >> 4;        // 0..3
    const int mrow = lane & 15;

    // staging source rows for this wave's 4 calls (A groups {wave, wave+4}, B same)
    int rA0 = bM + wave * 16 + mrow;        if (rA0 >= M) rA0 = M - 1;  // clamp: dup rows never stored
    int rA1 = bM + (wave + 4) * 16 + mrow;  if (rA1 >= M) rA1 = M - 1;
    const int rB0 = bN + wave * 16 + mrow;        // grid.x = N/BN exact -> always in range
    const int rB1 = bN + (wave + 4) * 16 + mrow;
    const unsigned short* gA0 = A  + (size_t)rA0 * K + q * 8;
    const unsigned short* gA1 = A  + (size_t)rA1 * K + q * 8;
    const unsigned short* gB0 = Bt + (size_t)rB0 * K + q * 8;
    const unsigned short* gB1 = Bt + (size_t)rB1 * K + q * 8;

    floatx4 acc[4][4];
#pragma unroll
    for (int i = 0; i < 4; i++)
#pragma unroll
        for (int j = 0; j < 4; j++) acc[i][j] = (floatx4)(0.0f);

    for (int kt = 0; kt < K; kt += BK) {
        gload_lds16(gA0 + kt, &As[wave][0]);
        gload_lds16(gA1 + kt, &As[wave + 4][0]);
        gload_lds16(gB0 + kt, &Bs[wave][0]);
        gload_lds16(gB1 + kt, &Bs[wave + 4][0]);
        __syncthreads();   // drains vmcnt (async LDS loads) + barrier

        bf16x8 af[4], bfv[4];
#pragma unroll
        for (int mi = 0; mi < 4; mi++)
            af[mi] = *(const bf16x8*)&As[(wave >> 1) * 4 + mi][lane * 8];
#pragma unroll
        for (int ni = 0; ni < 4; ni++)
            bfv[ni] = *(const bf16x8*)&Bs[(wave & 1) * 4 + ni][lane * 8];
#pragma unroll
        for (int mi = 0; mi < 4; mi++)
#pragma unroll
            for (int ni = 0; ni < 4; ni++)
                acc[mi][ni] = __builtin_amdgcn_mfma_f32_16x16x32_bf16(
                    af[mi], bfv[ni], acc[mi][ni], 0, 0, 0);
        __syncthreads();   // protect LDS from next-iter staging
    }

    // ---- epilogue: per-wave LDS repack (4 KB region) -> 16B/lane coalesced stores ----
    // acc C/D layout: col = mrow (lane&15), row = q*4 + r  (m89/m91-verified)
    unsigned short* lbuf = Sh + wave * 2048;   // 32 rows x 64 cols bf16 per pass
    float bv[4];
#pragma unroll
    for (int ni = 0; ni < 4; ni++) bv[ni] = bias[bN + wn + ni * 16 + mrow];

#pragma unroll
    for (int p = 0; p < 2; p++) {              // pass p covers mi = 2p, 2p+1 (32 rows)
#pragma unroll
        for (int mh = 0; mh < 2; mh++) {
            int mi = 2 * p + mh;
#pragma unroll
            for (int ni = 0; ni < 4; ni++)
#pragma unroll
                for (int r = 0; r < 4; r++)
                    lbuf[(mh * 16 + q * 4 + r) * 64 + ni * 16 + mrow] =
                        f2bf(acc[mi][ni][r] + bv[ni]);
        }
        // read back row-major: 8 lanes per row, 16B each -> 128B/row fully-dirty lines
#pragma unroll
        for (int i = 0; i < 4; i++) {
            int prow = i * 8 + (lane >> 3);
            int pcol = (lane & 7) * 8;
            int grow = bM + wm + p * 32 + prow;
            if (grow < M)
                *(ushortx8*)(C + (size_t)grow * N + bN + wn + pcol) =
                    *(const ushortx8*)&lbuf[prow * 64 + pcol];
        }
    }
}

// ---------- propagate step: one wave per destination node ----------
template <int VEC> struct VecT;
template <> struct VecT<8> { typedef ushortx8 type; };
template <> struct VecT<2> { typedef ushortx2 type; };

template <int VEC, bool ADD_SELF, bool RELU, bool OUT_F32>
__global__ __launch_bounds__(256) void prop_step_kernel(
    const unsigned short* __restrict__ cur,  // bf16 [Nn, F]
    void* __restrict__ outp,                 // bf16 or fp32 [Nn, F]
    const int* __restrict__ head,
    const int* __restrict__ nxt,
    const int* __restrict__ esrc,
    const int* __restrict__ emask,
    int kval, int Nn)
{
    typedef typename VecT<VEC>::type VT;
    const int w = blockIdx.x * 4 + (threadIdx.x >> 6);
    if (w >= Nn) return;
    const int lane = threadIdx.x & 63;
    const int F = VEC * 64;
    const size_t off = (size_t)w * F + lane * VEC;

    float acc[VEC];
    if (ADD_SELF) {
        VT v = *(const VT*)(cur + off);
#pragma unroll
        for (int i = 0; i < VEC; i++) acc[i] = bf2f(v[i]);
    } else {
#pragma unroll
        for (int i = 0; i < VEC; i++) acc[i] = 0.0f;
    }

    for (int e = head[w]; e >= 0; e = nxt[e]) {
        if (emask[e] == kval) {
            int s = esrc[e];
            VT v = *(const VT*)(cur + (size_t)s * F + lane * VEC);
#pragma unroll
            for (int i = 0; i < VEC; i++) acc[i] += bf2f(v[i]);
        }
    }

#pragma unroll
    for (int i = 0; i < VEC; i++)
        if (RELU && acc[i] < 0.0f) acc[i] = 0.0f;

    if (OUT_F32) {
        float* out = (float*)outp;
        float2 o2;
#pragma unroll
        for (int i = 0; i < VEC; i += 2) {
            o2.x = acc[i]; o2.y = acc[i + 1];
            *(float2*)(out + off + i) = o2;
        }
    } else {
        VT o;
#pragma unroll
        for (int i = 0; i < VEC; i++) o[i] = f2bf(acc[i]);
        *(VT*)((unsigned short*)outp + off) = o;
    }
}

// ---------- launch ----------
extern "C" void kernel_launch(void* const* d_in, const int* in_sizes, int n_in,
                              void* d_out, int out_size, void* d_ws, size_t ws_size,
                              hipStream_t stream)
{
    const float* x  = (const float*)d_in[0];       // [Nn, 512] fp32
    const int*   ei = (const int*)d_in[1];         // [2, E] int32
    const int*   em = (const int*)d_in[2];         // [E]
    const float* W1 = (const float*)d_in[5];       // [512,512]
    const float* b1 = (const float*)d_in[6];       // [512]
    const float* W2 = (const float*)d_in[7];       // [512,128]
    const float* b2 = (const float*)d_in[8];       // [128]

    const int FIN = 512, FOUT = 128;
    const int Nn = in_sizes[0] / FIN;   // 60000
    const int E  = in_sizes[2];         // 160000

    char* ws = (char*)d_ws;
    size_t off = 0;
    auto alloc = [&](size_t bytes) -> char* {
        char* p = ws + off;
        off += (bytes + 255) & ~(size_t)255;
        return p;
    };
    unsigned short* W1t = (unsigned short*)alloc((size_t)FIN * FIN * 2);
    unsigned short* W2t = (unsigned short*)alloc((size_t)FIN * FOUT * 2);
    unsigned short* xb  = (unsigned short*)alloc((size_t)Nn * FIN * 2); // reused as A1
    unsigned short* h1  = (unsigned short*)alloc((size_t)Nn * FIN * 2); // reused as B1
    unsigned short* h2  = (unsigned short*)alloc((size_t)Nn * FOUT * 2);
    unsigned short* A2  = (unsigned short*)alloc((size_t)Nn * FOUT * 2);
    int* head = (int*)alloc((size_t)Nn * 4);
    int* nxt  = (int*)alloc((size_t)E * 4);
    unsigned short* A1 = xb;
    (void)ws_size; (void)n_in; (void)out_size;

    // 1) convert x; transpose+convert weights
    cvt_f32_bf16_kernel<<<((Nn * FIN / 4) + 255) / 256, 256, 0, stream>>>(x, xb, Nn * FIN / 4);
    transpose_cvt_kernel<<<(FIN * FIN + 255) / 256, 256, 0, stream>>>(W1, W1t, FIN, FIN);
    transpose_cvt_kernel<<<(FIN * FOUT + 255) / 256, 256, 0, stream>>>(W2, W2t, FIN, FOUT);

    // 2) per-dst linked lists
    init_head_kernel<<<(Nn + 255) / 256, 256, 0, stream>>>(head, Nn);
    build_list_kernel<<<(E + 255) / 256, 256, 0, stream>>>(ei, E, head, nxt);

    // 3) h1 = x @ W1 + b1
    {
        dim3 grid(FIN / BN, (Nn + BM - 1) / BM);
        gemm_bt_bias<<<grid, 256, 0, stream>>>(xb, W1t, b1, h1, Nn, FIN, FIN);
    }

    // 4) P1: A1 = S0(h1);  B1 = relu(A1 + S1(A1))
    {
        int grid = (Nn + 3) / 4;
        prop_step_kernel<8, false, false, false><<<grid, 256, 0, stream>>>(h1, A1, head, nxt, ei, em, 0, Nn);
        prop_step_kernel<8, true,  true,  false><<<grid, 256, 0, stream>>>(A1, h1, head, nxt, ei, em, 1, Nn);
    }

    // 5) h2 = B1 @ W2 + b2
    {
        dim3 grid(FOUT / BN, (Nn + BM - 1) / BM);
        gemm_bt_bias<<<grid, 256, 0, stream>>>(h1, W2t, b2, h2, Nn, FOUT, FIN);
    }

    // 6) P2: A2 = S0(h2);  out = A2 + S1(A2)  (fp32)
    {
        int grid = (Nn + 3) / 4;
        prop_step_kernel<2, false, false, false><<<grid, 256, 0, stream>>>(h2, A2, head, nxt, ei, em, 0, Nn);
        prop_step_kernel<2, true,  false, true ><<<grid, 256, 0, stream>>>(A2, d_out, head, nxt, ei, em, 1, Nn);
    }
}

// Round 4
// 398.066 us; speedup vs baseline: 1.1835x; 1.1384x over previous
//
#include <hip/hip_runtime.h>

// ---------- types ----------
typedef __bf16 bf16x8 __attribute__((ext_vector_type(8)));
typedef float  floatx4 __attribute__((ext_vector_type(4)));
typedef unsigned short ushortx8 __attribute__((ext_vector_type(8)));
typedef unsigned short ushortx4 __attribute__((ext_vector_type(4)));
typedef unsigned short ushortx2 __attribute__((ext_vector_type(2)));

__device__ __forceinline__ float bf2f(unsigned short u) {
    return __uint_as_float(((unsigned)u) << 16);
}
__device__ __forceinline__ unsigned short f2bf(float f) {
    unsigned u = __float_as_uint(f);
    return (unsigned short)((u + 0x7FFFu + ((u >> 16) & 1u)) >> 16);
}

// async global->LDS, 16B per lane; lds dest = wave-uniform base + lane*16
__device__ __forceinline__ void gload_lds16(const unsigned short* g, unsigned short* l) {
    __builtin_amdgcn_global_load_lds(
        (const __attribute__((address_space(1))) void*)g,
        (__attribute__((address_space(3))) void*)l, 16, 0, 0);
}

// ---------- conversion / CSR helpers ----------
__global__ void cvt_f32_bf16_kernel(const float* __restrict__ in,
                                    unsigned short* __restrict__ out, int n4) {
    int i = blockIdx.x * blockDim.x + threadIdx.x;
    if (i >= n4) return;
    float4 v = ((const float4*)in)[i];
    ushortx4 o;
    o[0] = f2bf(v.x); o[1] = f2bf(v.y); o[2] = f2bf(v.z); o[3] = f2bf(v.w);
    ((ushortx4*)out)[i] = o;
}

__global__ void transpose_cvt_kernel(const float* __restrict__ in,
                                     unsigned short* __restrict__ out,
                                     int K, int N) {
    int idx = blockIdx.x * blockDim.x + threadIdx.x;
    if (idx >= K * N) return;
    int k = idx / N, n = idx - k * N;
    out[n * K + k] = f2bf(in[idx]);
}

__global__ void init_head_kernel(int* __restrict__ head, int n) {
    int i = blockIdx.x * blockDim.x + threadIdx.x;
    if (i < n) head[i] = -1;
}

// two lists per dst: head[mask*Nn + dst] — halves traversal length per step
__global__ void build_list_kernel(const int* __restrict__ ei, const int* __restrict__ em,
                                  int E, int Nn,
                                  int* __restrict__ head, int* __restrict__ nxt) {
    int e = blockIdx.x * blockDim.x + threadIdx.x;
    if (e >= E) return;
    int d = ei[E + e];
    int m = em[e];
    nxt[e] = atomicExch(&head[m * Nn + d], e);
}

// ---------- GEMM: C[M,N] = A[M,K] @ B[K,N] + bias; A bf16 row-major, Bt = B^T bf16 (N x K) ----------
// BK=64: 8 K-iterations (K=512), 32 MFMA/wave per barrier-drain; fragment-order
// global_load_lds staging; XCD-aware swizzle keeps the N-split blocks sharing an
// A-tile on one XCD (L2-local reuse).
#define BM 128
#define BN 128
#define BK 64

__global__ __launch_bounds__(256) void gemm_bt_bias(
    const unsigned short* __restrict__ A,    // M x K  (bf16 bits)
    const unsigned short* __restrict__ Bt,   // N x K  (bf16 bits)
    const float* __restrict__ bias,          // N (fp32)
    unsigned short* __restrict__ C,          // M x N  (bf16 bits)
    int M, int N, int K)
{
    // As group gg = s*8 + g (s = k-half, g = m-group): lane l holds
    //   A[bM + g*16 + (l&15)][kt + s*32 + (l>>4)*8 + 0..7]   (MFMA A-frag order)
    __shared__ unsigned short Sh[16384];     // 32 KB: As[16][512] + Bs[16][512]
    unsigned short (*As)[512] = (unsigned short(*)[512])Sh;
    unsigned short (*Bs)[512] = (unsigned short(*)[512])(Sh + 8192);

    const int tid  = threadIdx.x;
    const int lane = tid & 63;
    const int wave = tid >> 6;

    // XCD-aware swizzle (only for the N-split grid.x==4 case = GEMM1):
    // blocks sharing the same A-row-tile get ids differing by 8 -> same XCD (id%8).
    int bx, by;
    if (gridDim.x == 4) {
        int id = blockIdx.y * 4 + blockIdx.x;
        int full = (gridDim.y & ~7) * 4;
        if (id < full) {
            bx = (id >> 3) & 3;
            by = (id >> 5) * 8 + (id & 7);
        } else {
            int t = id - full;
            by = (gridDim.y & ~7) + (t >> 2);
            bx = t & 3;
        }
    } else {
        bx = blockIdx.x; by = blockIdx.y;
    }
    const int bM = by * BM;
    const int bN = bx * BN;
    const int wm = (wave >> 1) * 64;   // wave sub-tile origin (2x2 waves)
    const int wn = (wave & 1) * 64;
    const int q    = lane >> 4;        // 0..3
    const int mrow = lane & 15;

    // staging pointers: wave stages groups {wave, wave+4, wave+8, wave+12} of A and B
    const unsigned short* pA[4];
    const unsigned short* pB[4];
#pragma unroll
    for (int c = 0; c < 4; c++) {
        int gg = wave + 4 * c;
        int g7 = gg & 7, s = gg >> 3;
        int rA = bM + g7 * 16 + mrow; if (rA >= M) rA = M - 1;  // clamp: dup rows never stored
        int rB = bN + g7 * 16 + mrow;                           // grid.x exact -> in range
        pA[c] = A  + (size_t)rA * K + s * 32 + q * 8;
        pB[c] = Bt + (size_t)rB * K + s * 32 + q * 8;
    }

    floatx4 acc[4][4];
#pragma unroll
    for (int i = 0; i < 4; i++)
#pragma unroll
        for (int j = 0; j < 4; j++) acc[i][j] = (floatx4)(0.0f);

    for (int kt = 0; kt < K; kt += BK) {
#pragma unroll
        for (int c = 0; c < 4; c++) {
            gload_lds16(pA[c] + kt, &As[wave + 4 * c][0]);
            gload_lds16(pB[c] + kt, &Bs[wave + 4 * c][0]);
        }
        __syncthreads();   // drains vmcnt (async LDS loads) + barrier

#pragma unroll
        for (int s = 0; s < 2; s++) {
            bf16x8 af[4], bfv[4];
#pragma unroll
            for (int mi = 0; mi < 4; mi++)
                af[mi] = *(const bf16x8*)&As[s * 8 + (wave >> 1) * 4 + mi][lane * 8];
#pragma unroll
            for (int ni = 0; ni < 4; ni++)
                bfv[ni] = *(const bf16x8*)&Bs[s * 8 + (wave & 1) * 4 + ni][lane * 8];
#pragma unroll
            for (int mi = 0; mi < 4; mi++)
#pragma unroll
                for (int ni = 0; ni < 4; ni++)
                    acc[mi][ni] = __builtin_amdgcn_mfma_f32_16x16x32_bf16(
                        af[mi], bfv[ni], acc[mi][ni], 0, 0, 0);
        }
        __syncthreads();   // protect LDS from next-iter staging
    }

    // ---- epilogue: per-wave LDS repack -> 16B/lane coalesced stores ----
    // acc C/D layout: col = mrow, row = q*4 + r  (m89/m91-verified)
    unsigned short* lbuf = Sh + wave * 2048;   // private 4 KB per wave
    float bv[4];
#pragma unroll
    for (int ni = 0; ni < 4; ni++) bv[ni] = bias[bN + wn + ni * 16 + mrow];

#pragma unroll
    for (int p = 0; p < 2; p++) {              // pass p covers mi = 2p, 2p+1 (32 rows)
#pragma unroll
        for (int mh = 0; mh < 2; mh++) {
            int mi = 2 * p + mh;
#pragma unroll
            for (int ni = 0; ni < 4; ni++)
#pragma unroll
                for (int r = 0; r < 4; r++)
                    lbuf[(mh * 16 + q * 4 + r) * 64 + ni * 16 + mrow] =
                        f2bf(acc[mi][ni][r] + bv[ni]);
        }
#pragma unroll
        for (int i = 0; i < 4; i++) {
            int prow = i * 8 + (lane >> 3);
            int pcol = (lane & 7) * 8;
            int grow = bM + wm + p * 32 + prow;
            if (grow < M)
                *(ushortx8*)(C + (size_t)grow * N + bN + wn + pcol) =
                    *(const ushortx8*)&lbuf[prow * 64 + pcol];
        }
    }
}

// ---------- propagate step: one wave per destination node, per-mask edge list ----------
template <int VEC> struct VecT;
template <> struct VecT<8> { typedef ushortx8 type; };
template <> struct VecT<2> { typedef ushortx2 type; };

template <int VEC, bool ADD_SELF, bool RELU, bool OUT_F32>
__global__ __launch_bounds__(256) void prop_step_kernel(
    const unsigned short* __restrict__ cur,  // bf16 [Nn, F]
    void* __restrict__ outp,                 // bf16 or fp32 [Nn, F]
    const int* __restrict__ head,            // per-mask list heads (pre-offset)
    const int* __restrict__ nxt,
    const int* __restrict__ esrc,
    int Nn)
{
    typedef typename VecT<VEC>::type VT;
    const int w = blockIdx.x * 4 + (threadIdx.x >> 6);
    if (w >= Nn) return;
    const int lane = threadIdx.x & 63;
    const int F = VEC * 64;
    const size_t off = (size_t)w * F + lane * VEC;

    float acc[VEC];
    if (ADD_SELF) {
        VT v = *(const VT*)(cur + off);
#pragma unroll
        for (int i = 0; i < VEC; i++) acc[i] = bf2f(v[i]);
    } else {
#pragma unroll
        for (int i = 0; i < VEC; i++) acc[i] = 0.0f;
    }

    for (int e = head[w]; e >= 0; e = nxt[e]) {
        int s = esrc[e];
        VT v = *(const VT*)(cur + (size_t)s * F + lane * VEC);
#pragma unroll
        for (int i = 0; i < VEC; i++) acc[i] += bf2f(v[i]);
    }

#pragma unroll
    for (int i = 0; i < VEC; i++)
        if (RELU && acc[i] < 0.0f) acc[i] = 0.0f;

    if (OUT_F32) {
        float* out = (float*)outp;
        float2 o2;
#pragma unroll
        for (int i = 0; i < VEC; i += 2) {
            o2.x = acc[i]; o2.y = acc[i + 1];
            *(float2*)(out + off + i) = o2;
        }
    } else {
        VT o;
#pragma unroll
        for (int i = 0; i < VEC; i++) o[i] = f2bf(acc[i]);
        *(VT*)((unsigned short*)outp + off) = o;
    }
}

// ---------- launch ----------
extern "C" void kernel_launch(void* const* d_in, const int* in_sizes, int n_in,
                              void* d_out, int out_size, void* d_ws, size_t ws_size,
                              hipStream_t stream)
{
    const float* x  = (const float*)d_in[0];       // [Nn, 512] fp32
    const int*   ei = (const int*)d_in[1];         // [2, E] int32
    const int*   em = (const int*)d_in[2];         // [E]
    const float* W1 = (const float*)d_in[5];       // [512,512]
    const float* b1 = (const float*)d_in[6];       // [512]
    const float* W2 = (const float*)d_in[7];       // [512,128]
    const float* b2 = (const float*)d_in[8];       // [128]

    const int FIN = 512, FOUT = 128;
    const int Nn = in_sizes[0] / FIN;   // 60000
    const int E  = in_sizes[2];         // 160000

    char* ws = (char*)d_ws;
    size_t off = 0;
    auto alloc = [&](size_t bytes) -> char* {
        char* p = ws + off;
        off += (bytes + 255) & ~(size_t)255;
        return p;
    };
    unsigned short* W1t = (unsigned short*)alloc((size_t)FIN * FIN * 2);
    unsigned short* W2t = (unsigned short*)alloc((size_t)FIN * FOUT * 2);
    unsigned short* xb  = (unsigned short*)alloc((size_t)Nn * FIN * 2); // reused as A1
    unsigned short* h1  = (unsigned short*)alloc((size_t)Nn * FIN * 2); // reused as B1
    unsigned short* h2  = (unsigned short*)alloc((size_t)Nn * FOUT * 2);
    unsigned short* A2  = (unsigned short*)alloc((size_t)Nn * FOUT * 2);
    int* head = (int*)alloc((size_t)2 * Nn * 4);   // [2][Nn]
    int* nxt  = (int*)alloc((size_t)E * 4);
    unsigned short* A1 = xb;
    (void)ws_size; (void)n_in; (void)out_size;

    // 1) convert x; transpose+convert weights
    cvt_f32_bf16_kernel<<<((Nn * FIN / 4) + 255) / 256, 256, 0, stream>>>(x, xb, Nn * FIN / 4);
    transpose_cvt_kernel<<<(FIN * FIN + 255) / 256, 256, 0, stream>>>(W1, W1t, FIN, FIN);
    transpose_cvt_kernel<<<(FIN * FOUT + 255) / 256, 256, 0, stream>>>(W2, W2t, FIN, FOUT);

    // 2) per-(mask,dst) linked lists
    init_head_kernel<<<(2 * Nn + 255) / 256, 256, 0, stream>>>(head, 2 * Nn);
    build_list_kernel<<<(E + 255) / 256, 256, 0, stream>>>(ei, em, E, Nn, head, nxt);

    // 3) h1 = x @ W1 + b1
    {
        dim3 grid(FIN / BN, (Nn + BM - 1) / BM);
        gemm_bt_bias<<<grid, 256, 0, stream>>>(xb, W1t, b1, h1, Nn, FIN, FIN);
    }

    // 4) P1: A1 = S0(h1);  B1 = relu(A1 + S1(A1))
    {
        int grid = (Nn + 3) / 4;
        prop_step_kernel<8, false, false, false><<<grid, 256, 0, stream>>>(h1, A1, head,      nxt, ei, Nn);
        prop_step_kernel<8, true,  true,  false><<<grid, 256, 0, stream>>>(A1, h1, head + Nn, nxt, ei, Nn);
    }

    // 5) h2 = B1 @ W2 + b2
    {
        dim3 grid(FOUT / BN, (Nn + BM - 1) / BM);
        gemm_bt_bias<<<grid, 256, 0, stream>>>(h1, W2t, b2, h2, Nn, FOUT, FIN);
    }

    // 6) P2: A2 = S0(h2);  out = A2 + S1(A2)  (fp32)
    {
        int grid = (Nn + 3) / 4;
        prop_step_kernel<2, false, false, false><<<grid, 256, 0, stream>>>(h2, A2, head,      nxt, ei, Nn);
        prop_step_kernel<2, true,  false, true ><<<grid, 256, 0, stream>>>(A2, d_out, head + Nn, nxt, ei, Nn);
    }
}